// Round 23
// baseline (65.090 us; speedup 1.0000x reference)
//
#include <hip/hip_runtime.h>
#include <hip/hip_fp16.h>

#define W 144
#define PLANE (W * W)
#define VOL (W * W * W)
#define NB 2
#define WIN 11
#define PAD 5
#define YCH 12
#define YC (W / YCH)           // 12
#define NSTEPS (YC + 2 * PAD)  // 22
#define ZCH 16
#define ZCL (W / ZCH)          // 9
#define WPB 2
#define NXCD 8
#define NWAVES (NB * W * YCH)        // 3456
#define NZB (NB * (W / 2) * ZCH)     // 2304

// DPP lane shift with old=0 (edge/exec-off lanes read 0).
template <int CTRL>
__device__ __forceinline__ float dpp0(float x) {
    return __int_as_float(
        __builtin_amdgcn_update_dpp(0, __float_as_int(x), CTRL, 0xf, 0xf, false));
}
#define SHR1(v) dpp0<0x138>(v)
#define SHL1(v) dpp0<0x130>(v)

// Lane l holds v at x = 4l-8 .. 4l-5. 11-tap x-window sums for its 4 positions
// using only wave shifts (verified on-chip R8/R12/R13/R14, absmax 0).
__device__ __forceinline__ float4 win11x4(const float4 v) {
    const float pre2 = v.x + v.y;
    const float pre3 = pre2 + v.z;
    const float q = pre3 + v.w;
    const float suf2 = v.z + v.w;
    const float suf3 = suf2 + v.y;
    const float qm1 = SHR1(q);
    const float sfx2m1 = SHR1(suf2);
    const float sfx3m1 = SHR1(suf3);
    const float sfx1m2 = SHR1(SHR1(v.w));
    const float qp1 = SHL1(q);
    const float pfx2p1 = SHL1(pre2);
    const float pfx3p1 = SHL1(pre3);
    const float pfx1p2 = SHL1(SHL1(v.x));
    float4 w;
    w.x = (sfx1m2 + qm1) + (q + pfx2p1);
    w.y = qm1 + (q + pfx3p1);
    w.z = sfx3m1 + (q + qp1);
    w.w = (sfx2m1 + q) + (qp1 + pfx1p2);
    return w;
}

__device__ __forceinline__ uint2 pack4h(float a, float b, float c, float d) {
    const __half2 lo = __floats2half2_rn(a, b);
    const __half2 hi = __floats2half2_rn(c, d);
    uint2 r;
    r.x = __builtin_bit_cast(unsigned int, lo);
    r.y = __builtin_bit_cast(unsigned int, hi);
    return r;
}

__device__ __forceinline__ float4 unpack4h(unsigned int lo, unsigned int hi) {
    const float2 flo = __half22float2(__builtin_bit_cast(__half2, lo));
    const float2 fhi = __half22float2(__builtin_bit_cast(__half2, hi));
    return make_float4(flo.x, flo.y, fhi.x, fhi.y);
}

// kF: ringless fat-4 x+y pass, ROLLED 22-step loop, fp16 ws in [b][y][z][x]
// layout. WPB=2: finer block granularity for dispatch/drain (R16: best occupancy).
__global__ __launch_bounds__(WPB * 64) void
kF_xypass(const float* __restrict__ pred, const float* __restrict__ targ,
          uint2* __restrict__ wsh, double* __restrict__ slotW) {
    const int tid = threadIdx.x;
    const int l = tid & 63;
    const int wid = tid >> 6;

    // bijective XCD swizzle (nwg % 8 == 0)
    const int nwg = NWAVES / WPB;         // 1728
    const int q = nwg / NXCD;             // 216
    const int hw = (int)blockIdx.x;
    const int logical = (hw % NXCD) * q + hw / NXCD;

    int wg = logical * WPB + wid;
    const int yc = wg % YCH; wg /= YCH;
    const int z = wg % W; wg /= W;
    const int b = wg;
    const int y0 = yc * YC;

    const int xbase = 4 * l - 8;                 // lanes 2..37 own x 0..143
    const bool vx = (xbase >= 0) && (xbase < W);
    const float* __restrict__ gp = pred + (size_t)b * VOL + (size_t)z * PLANE + xbase;
    const float* __restrict__ gt = targ + (size_t)b * VOL + (size_t)z * PLANE + xbase;

    const float4 z4 = make_float4(0.f, 0.f, 0.f, 0.f);
    float l1 = 0.f;

    if (vx) {
        float4 s_p = z4, s_t = z4, s_pt = z4, s_sq = z4;
        float4 pa = z4, ta = z4, pn = z4, tn = z4, po = z4, to = z4;

        {
            const int g0 = y0 - PAD;
            if (g0 >= 0) {
                pa = *reinterpret_cast<const float4*>(gp + (size_t)g0 * W);
                ta = *reinterpret_cast<const float4*>(gt + (size_t)g0 * W);
            }
            const int g1 = y0 - PAD + 1;
            if (g1 >= 0) {
                pn = *reinterpret_cast<const float4*>(gp + (size_t)g1 * W);
                tn = *reinterpret_cast<const float4*>(gt + (size_t)g1 * W);
            }
        }

        uint2* outp = wsh + (size_t)b * VOL + (size_t)y0 * PLANE + (size_t)z * W + xbase;

#pragma unroll 1
        for (int i = 0; i < NSTEPS; ++i) {
            const float4 p4 = pa, t4 = ta;
            pa = pn; ta = tn;
            {
                const int g = y0 - PAD + i + 2;
                if (i < NSTEPS - 2 && g >= 0 && g < W) {
                    pn = *reinterpret_cast<const float4*>(gp + (size_t)g * W);
                    tn = *reinterpret_cast<const float4*>(gt + (size_t)g * W);
                } else {
                    pn = z4; tn = z4;
                }
            }

            if (i >= PAD && i < PAD + YC) {
                l1 += (fabsf(p4.x - t4.x) + fabsf(p4.y - t4.y)) +
                      (fabsf(p4.z - t4.z) + fabsf(p4.w - t4.w));
            }

            s_p.x += p4.x; s_p.y += p4.y; s_p.z += p4.z; s_p.w += p4.w;
            s_t.x += t4.x; s_t.y += t4.y; s_t.z += t4.z; s_t.w += t4.w;
            s_pt.x += p4.x * t4.x; s_pt.y += p4.y * t4.y;
            s_pt.z += p4.z * t4.z; s_pt.w += p4.w * t4.w;
            s_sq.x += fmaf(p4.x, p4.x, t4.x * t4.x);
            s_sq.y += fmaf(p4.y, p4.y, t4.y * t4.y);
            s_sq.z += fmaf(p4.z, p4.z, t4.z * t4.z);
            s_sq.w += fmaf(p4.w, p4.w, t4.w * t4.w);

            if (i >= WIN) {
                s_p.x -= po.x; s_p.y -= po.y; s_p.z -= po.z; s_p.w -= po.w;
                s_t.x -= to.x; s_t.y -= to.y; s_t.z -= to.z; s_t.w -= to.w;
                s_pt.x -= po.x * to.x; s_pt.y -= po.y * to.y;
                s_pt.z -= po.z * to.z; s_pt.w -= po.w * to.w;
                s_sq.x -= fmaf(po.x, po.x, to.x * to.x);
                s_sq.y -= fmaf(po.y, po.y, to.y * to.y);
                s_sq.z -= fmaf(po.z, po.z, to.z * to.z);
                s_sq.w -= fmaf(po.w, po.w, to.w * to.w);
            }

            if (i >= 2 * PAD) {
                if (i < NSTEPS - 1) {  // prefetch old row for step i+1's subtract
                    const int g = y0 + i - 15;  // (i+1) - 11 - PAD + y0
                    if (g >= 0) {
                        po = *reinterpret_cast<const float4*>(gp + (size_t)g * W);
                        to = *reinterpret_cast<const float4*>(gt + (size_t)g * W);
                    } else {
                        po = z4; to = z4;
                    }
                }
                const float4 w0 = win11x4(s_p);
                const float4 w1 = win11x4(s_t);
                const float4 w2 = win11x4(s_pt);
                const float4 w3 = win11x4(s_sq);
                const uint2 q0 = pack4h(w0.x, w1.x, w2.x, w3.x);
                const uint2 q1 = pack4h(w0.y, w1.y, w2.y, w3.y);
                const uint2 q2 = pack4h(w0.z, w1.z, w2.z, w3.z);
                const uint2 q3 = pack4h(w0.w, w1.w, w2.w, w3.w);
                uint4* o4 = reinterpret_cast<uint4*>(outp);
                o4[0] = make_uint4(q0.x, q0.y, q1.x, q1.y);
                o4[1] = make_uint4(q2.x, q2.y, q3.x, q3.y);
                outp += PLANE;
            }
        }
    }

    l1 += __shfl_xor(l1, 32);
    l1 += __shfl_xor(l1, 16);
    l1 += __shfl_xor(l1, 8);
    l1 += __shfl_xor(l1, 4);
    l1 += __shfl_xor(l1, 2);
    l1 += __shfl_xor(l1, 1);
    if (l == 0) slotW[logical * WPB + wid] = (double)l1;
}

// K3: wide-load ringless z-pass (verified R19/R21). ZCH=16 for more
// latency-parallelism. Block = (b, y-pair, z-chunk), 144 threads.
__global__ void k3_zpass(const uint2* __restrict__ wsh, double* __restrict__ slotS) {
    const int t = threadIdx.x;
    int bid = blockIdx.x;
    const int c = bid % ZCH; bid /= ZCH;
    const int yp = bid % (W / 2); bid /= (W / 2);
    const int b = bid;
    const int y = 2 * yp + (t / 72);
    const int xp = t % 72;
    const int zstart = c * ZCL;

    const uint2* F = wsh + (size_t)b * VOL + (size_t)y * PLANE + 2 * xp;

    float a0 = 0.f, a1 = 0.f, a2 = 0.f, a3 = 0.f;
    float b0 = 0.f, b1 = 0.f, b2 = 0.f, b3 = 0.f;
    const float inv = 1.0f / 1331.0f;
    const float C1 = 0.01f * 0.01f;
    const float C2 = 0.03f * 0.03f;
    float ssim_acc = 0.f;

    const int NZ = ZCL + 2 * PAD;  // 19
#pragma unroll 1
    for (int i = 0; i < NZ; ++i) {
        const int zl = zstart - PAD + i;
        if (zl >= 0 && zl < W) {
            const uint4 uu = *reinterpret_cast<const uint4*>(F + (size_t)zl * W);
            const float4 vA = unpack4h(uu.x, uu.y);
            const float4 vB = unpack4h(uu.z, uu.w);
            a0 += vA.x; a1 += vA.y; a2 += vA.z; a3 += vA.w;
            b0 += vB.x; b1 += vB.y; b2 += vB.z; b3 += vB.w;
        }
        const int zo = zl - WIN;
        if (i >= WIN && zo >= 0) {
            const uint4 uu = *reinterpret_cast<const uint4*>(F + (size_t)zo * W);
            const float4 vA = unpack4h(uu.x, uu.y);
            const float4 vB = unpack4h(uu.z, uu.w);
            a0 -= vA.x; a1 -= vA.y; a2 -= vA.z; a3 -= vA.w;
            b0 -= vB.x; b1 -= vB.y; b2 -= vB.z; b3 -= vB.w;
        }
        if (i >= 2 * PAD) {
            {
                const float mu_p = a0 * inv, mu_t = a1 * inv;
                const float ept = a2 * inv, esq = a3 * inv;
                const float mupt = mu_p * mu_t;
                const float musq = mu_p * mu_p + mu_t * mu_t;
                const float num = (2.f * mupt + C1) * (2.f * (ept - mupt) + C2);
                const float den = (musq + C1) * ((esq - musq) + C2);
                ssim_acc += num / den;
            }
            {
                const float mu_p = b0 * inv, mu_t = b1 * inv;
                const float ept = b2 * inv, esq = b3 * inv;
                const float mupt = mu_p * mu_t;
                const float musq = mu_p * mu_p + mu_t * mu_t;
                const float num = (2.f * mupt + C1) * (2.f * (ept - mupt) + C2);
                const float den = (musq + C1) * ((esq - musq) + C2);
                ssim_acc += num / den;
            }
        }
    }

    __shared__ float red[W];
    red[t] = ssim_acc;
    __syncthreads();
    if (t < 16) {
        float s2r = 0.f;
#pragma unroll
        for (int k = 0; k < 9; ++k) s2r += red[t + 16 * k];
        s2r += __shfl_down(s2r, 8);
        s2r += __shfl_down(s2r, 4);
        s2r += __shfl_down(s2r, 2);
        s2r += __shfl_down(s2r, 1);
        if (t == 0) slotS[blockIdx.x] = (double)s2r;
    }
}

// K4: reduce the 3456 + 2304 slots, write the 3 outputs. Deterministic order.
__global__ void k4_final(const double* __restrict__ slotW,
                         const double* __restrict__ slotS, float* __restrict__ out) {
    const int x = threadIdx.x;
    double a = 0.0, s = 0.0;
    for (int i = x; i < NWAVES; i += 256) a += slotW[i];
    for (int i = x; i < NZB; i += 256) s += slotS[i];
    __shared__ double d1[256];
    __shared__ double d2[256];
    d1[x] = a; d2[x] = s;
    __syncthreads();
    for (int st = 128; st > 0; st >>= 1) {
        if (x < st) { d1[x] += d1[x + st]; d2[x] += d2[x + st]; }
        __syncthreads();
    }
    if (x == 0) {
        const double n = (double)NB * (double)VOL;
        const double l1 = d1[0] / n;
        const double ssim_loss = 1.0 - d2[0] / n;
        out[0] = (float)(l1 + 0.5 * ssim_loss);
        out[1] = (float)l1;
        out[2] = (float)ssim_loss;
    }
}

extern "C" void kernel_launch(void* const* d_in, const int* in_sizes, int n_in,
                              void* d_out, int out_size, void* d_ws, size_t ws_size,
                              hipStream_t stream) {
    const float* pred = (const float*)d_in[0];
    const float* targ = (const float*)d_in[1];
    float* out = (float*)d_out;
    uint2* wsh = (uint2*)d_ws;                                  // half4 per voxel, 47.8 MB
    double* slotW = (double*)((char*)d_ws + (size_t)NB * VOL * sizeof(uint2));
    double* slotS = slotW + NWAVES;

    const int nwg = NWAVES / WPB;  // 1728 blocks
    kF_xypass<<<nwg, WPB * 64, 0, stream>>>(pred, targ, wsh, slotW);
    k3_zpass<<<NZB, W, 0, stream>>>(wsh, slotS);
    k4_final<<<1, 256, 0, stream>>>(slotW, slotS, out);
}

// Round 24
// 62.842 us; speedup vs baseline: 1.0358x; 1.0358x over previous
//
#include <hip/hip_runtime.h>
#include <hip/hip_fp16.h>

#define W 144
#define PLANE (W * W)
#define VOL (W * W * W)
#define NB 2
#define WIN 11
#define PAD 5
#define YCH 12
#define YC (W / YCH)           // 12
#define NSTEPS (YC + 2 * PAD)  // 22
#define ZCH 12
#define ZCL (W / ZCH)          // 12
#define WPB 4
#define NXCD 8
#define NWAVES (NB * (W / 2) * YCH)  // 1728 (2 z-planes per wave)
#define NZB (NB * (W / 2) * ZCH)     // 1728

// DPP lane shift with old=0 (edge/exec-off lanes read 0).
template <int CTRL>
__device__ __forceinline__ float dpp0(float x) {
    return __int_as_float(
        __builtin_amdgcn_update_dpp(0, __float_as_int(x), CTRL, 0xf, 0xf, false));
}
#define SHR1(v) dpp0<0x138>(v)
#define SHL1(v) dpp0<0x130>(v)

// Lane l holds v at x = 4l-8 .. 4l-5. 11-tap x-window sums for its 4 positions
// using only wave shifts (verified on-chip R8/R12/R13/R14, absmax 0).
__device__ __forceinline__ float4 win11x4(const float4 v) {
    const float pre2 = v.x + v.y;
    const float pre3 = pre2 + v.z;
    const float q = pre3 + v.w;
    const float suf2 = v.z + v.w;
    const float suf3 = suf2 + v.y;
    const float qm1 = SHR1(q);
    const float sfx2m1 = SHR1(suf2);
    const float sfx3m1 = SHR1(suf3);
    const float sfx1m2 = SHR1(SHR1(v.w));
    const float qp1 = SHL1(q);
    const float pfx2p1 = SHL1(pre2);
    const float pfx3p1 = SHL1(pre3);
    const float pfx1p2 = SHL1(SHL1(v.x));
    float4 w;
    w.x = (sfx1m2 + qm1) + (q + pfx2p1);
    w.y = qm1 + (q + pfx3p1);
    w.z = sfx3m1 + (q + qp1);
    w.w = (sfx2m1 + q) + (qp1 + pfx1p2);
    return w;
}

__device__ __forceinline__ uint2 pack4h(float a, float b, float c, float d) {
    const __half2 lo = __floats2half2_rn(a, b);
    const __half2 hi = __floats2half2_rn(c, d);
    uint2 r;
    r.x = __builtin_bit_cast(unsigned int, lo);
    r.y = __builtin_bit_cast(unsigned int, hi);
    return r;
}

__device__ __forceinline__ float4 unpack4h(unsigned int lo, unsigned int hi) {
    const float2 flo = __half22float2(__builtin_bit_cast(__half2, lo));
    const float2 fhi = __half22float2(__builtin_bit_cast(__half2, hi));
    return make_float4(flo.x, flo.y, fhi.x, fhi.y);
}

// kG: ringless fat-4 x+y pass with TWO z-planes per wave (ILP-2: two
// independent dependency chains interleaved in one instruction stream).
// ROLLED 22-step loop, fp16 ws in [b][y][z][x] layout.
__global__ __launch_bounds__(WPB * 64) void
kG_xypass(const float* __restrict__ pred, const float* __restrict__ targ,
          uint2* __restrict__ wsh, double* __restrict__ slotW) {
    const int tid = threadIdx.x;
    const int l = tid & 63;
    const int wid = tid >> 6;

    // bijective XCD swizzle (nwg % 8 == 0)
    const int nwg = NWAVES / WPB;         // 432
    const int q = nwg / NXCD;             // 54
    const int hw = (int)blockIdx.x;
    const int logical = (hw % NXCD) * q + hw / NXCD;

    int wg = logical * WPB + wid;
    const int yc = wg % YCH; wg /= YCH;
    const int zp = wg % (W / 2); wg /= (W / 2);
    const int b = wg;
    const int y0 = yc * YC;
    const int z0 = 2 * zp;

    const int xbase = 4 * l - 8;                 // lanes 2..37 own x 0..143
    const bool vx = (xbase >= 0) && (xbase < W);
    const float* __restrict__ gp0 = pred + (size_t)b * VOL + (size_t)z0 * PLANE + xbase;
    const float* __restrict__ gt0 = targ + (size_t)b * VOL + (size_t)z0 * PLANE + xbase;
    const float* __restrict__ gp1 = gp0 + PLANE;
    const float* __restrict__ gt1 = gt0 + PLANE;

    const float4 z4 = make_float4(0.f, 0.f, 0.f, 0.f);
    float l1 = 0.f;

    if (vx) {
        float4 sp0 = z4, st0 = z4, spt0 = z4, ssq0 = z4;
        float4 sp1 = z4, st1 = z4, spt1 = z4, ssq1 = z4;
        float4 pa0 = z4, ta0 = z4, pn0 = z4, tn0 = z4, po0 = z4, to0 = z4;
        float4 pa1 = z4, ta1 = z4, pn1 = z4, tn1 = z4, po1 = z4, to1 = z4;

        {
            const int g0 = y0 - PAD;
            if (g0 >= 0) {
                pa0 = *reinterpret_cast<const float4*>(gp0 + (size_t)g0 * W);
                ta0 = *reinterpret_cast<const float4*>(gt0 + (size_t)g0 * W);
                pa1 = *reinterpret_cast<const float4*>(gp1 + (size_t)g0 * W);
                ta1 = *reinterpret_cast<const float4*>(gt1 + (size_t)g0 * W);
            }
            const int g1 = y0 - PAD + 1;
            if (g1 >= 0) {
                pn0 = *reinterpret_cast<const float4*>(gp0 + (size_t)g1 * W);
                tn0 = *reinterpret_cast<const float4*>(gt0 + (size_t)g1 * W);
                pn1 = *reinterpret_cast<const float4*>(gp1 + (size_t)g1 * W);
                tn1 = *reinterpret_cast<const float4*>(gt1 + (size_t)g1 * W);
            }
        }

        // ws layout [b][y][z][x]: plane z0 at +z0*W, plane z1 at +W more.
        uint2* outp0 = wsh + (size_t)b * VOL + (size_t)y0 * PLANE + (size_t)z0 * W + xbase;
        uint2* outp1 = outp0 + W;

#pragma unroll 1
        for (int i = 0; i < NSTEPS; ++i) {
            const float4 p40 = pa0, t40 = ta0, p41 = pa1, t41 = ta1;
            pa0 = pn0; ta0 = tn0; pa1 = pn1; ta1 = tn1;
            {
                const int g = y0 - PAD + i + 2;
                if (i < NSTEPS - 2 && g >= 0 && g < W) {
                    pn0 = *reinterpret_cast<const float4*>(gp0 + (size_t)g * W);
                    tn0 = *reinterpret_cast<const float4*>(gt0 + (size_t)g * W);
                    pn1 = *reinterpret_cast<const float4*>(gp1 + (size_t)g * W);
                    tn1 = *reinterpret_cast<const float4*>(gt1 + (size_t)g * W);
                } else {
                    pn0 = z4; tn0 = z4; pn1 = z4; tn1 = z4;
                }
            }

            if (i >= PAD && i < PAD + YC) {
                l1 += (fabsf(p40.x - t40.x) + fabsf(p40.y - t40.y)) +
                      (fabsf(p40.z - t40.z) + fabsf(p40.w - t40.w));
                l1 += (fabsf(p41.x - t41.x) + fabsf(p41.y - t41.y)) +
                      (fabsf(p41.z - t41.z) + fabsf(p41.w - t41.w));
            }

            // add new rows (both planes — independent chains)
            sp0.x += p40.x; sp0.y += p40.y; sp0.z += p40.z; sp0.w += p40.w;
            st0.x += t40.x; st0.y += t40.y; st0.z += t40.z; st0.w += t40.w;
            spt0.x += p40.x * t40.x; spt0.y += p40.y * t40.y;
            spt0.z += p40.z * t40.z; spt0.w += p40.w * t40.w;
            ssq0.x += fmaf(p40.x, p40.x, t40.x * t40.x);
            ssq0.y += fmaf(p40.y, p40.y, t40.y * t40.y);
            ssq0.z += fmaf(p40.z, p40.z, t40.z * t40.z);
            ssq0.w += fmaf(p40.w, p40.w, t40.w * t40.w);

            sp1.x += p41.x; sp1.y += p41.y; sp1.z += p41.z; sp1.w += p41.w;
            st1.x += t41.x; st1.y += t41.y; st1.z += t41.z; st1.w += t41.w;
            spt1.x += p41.x * t41.x; spt1.y += p41.y * t41.y;
            spt1.z += p41.z * t41.z; spt1.w += p41.w * t41.w;
            ssq1.x += fmaf(p41.x, p41.x, t41.x * t41.x);
            ssq1.y += fmaf(p41.y, p41.y, t41.y * t41.y);
            ssq1.z += fmaf(p41.z, p41.z, t41.z * t41.z);
            ssq1.w += fmaf(p41.w, p41.w, t41.w * t41.w);

            if (i >= WIN) {  // subtract rows (i-11), prefetched last step
                sp0.x -= po0.x; sp0.y -= po0.y; sp0.z -= po0.z; sp0.w -= po0.w;
                st0.x -= to0.x; st0.y -= to0.y; st0.z -= to0.z; st0.w -= to0.w;
                spt0.x -= po0.x * to0.x; spt0.y -= po0.y * to0.y;
                spt0.z -= po0.z * to0.z; spt0.w -= po0.w * to0.w;
                ssq0.x -= fmaf(po0.x, po0.x, to0.x * to0.x);
                ssq0.y -= fmaf(po0.y, po0.y, to0.y * to0.y);
                ssq0.z -= fmaf(po0.z, po0.z, to0.z * to0.z);
                ssq0.w -= fmaf(po0.w, po0.w, to0.w * to0.w);

                sp1.x -= po1.x; sp1.y -= po1.y; sp1.z -= po1.z; sp1.w -= po1.w;
                st1.x -= to1.x; st1.y -= to1.y; st1.z -= to1.z; st1.w -= to1.w;
                spt1.x -= po1.x * to1.x; spt1.y -= po1.y * to1.y;
                spt1.z -= po1.z * to1.z; spt1.w -= po1.w * to1.w;
                ssq1.x -= fmaf(po1.x, po1.x, to1.x * to1.x);
                ssq1.y -= fmaf(po1.y, po1.y, to1.y * to1.y);
                ssq1.z -= fmaf(po1.z, po1.z, to1.z * to1.z);
                ssq1.w -= fmaf(po1.w, po1.w, to1.w * to1.w);
            }

            if (i >= 2 * PAD) {
                if (i < NSTEPS - 1) {  // prefetch old rows for step i+1's subtract
                    const int g = y0 + i - 15;  // (i+1) - 11 - PAD + y0
                    if (g >= 0) {
                        po0 = *reinterpret_cast<const float4*>(gp0 + (size_t)g * W);
                        to0 = *reinterpret_cast<const float4*>(gt0 + (size_t)g * W);
                        po1 = *reinterpret_cast<const float4*>(gp1 + (size_t)g * W);
                        to1 = *reinterpret_cast<const float4*>(gt1 + (size_t)g * W);
                    } else {
                        po0 = z4; to0 = z4; po1 = z4; to1 = z4;
                    }
                }
                {
                    const float4 w0 = win11x4(sp0);
                    const float4 w1 = win11x4(st0);
                    const float4 w2 = win11x4(spt0);
                    const float4 w3 = win11x4(ssq0);
                    const uint2 q0 = pack4h(w0.x, w1.x, w2.x, w3.x);
                    const uint2 q1 = pack4h(w0.y, w1.y, w2.y, w3.y);
                    const uint2 q2 = pack4h(w0.z, w1.z, w2.z, w3.z);
                    const uint2 q3 = pack4h(w0.w, w1.w, w2.w, w3.w);
                    uint4* o4 = reinterpret_cast<uint4*>(outp0);
                    o4[0] = make_uint4(q0.x, q0.y, q1.x, q1.y);
                    o4[1] = make_uint4(q2.x, q2.y, q3.x, q3.y);
                    outp0 += PLANE;
                }
                {
                    const float4 w0 = win11x4(sp1);
                    const float4 w1 = win11x4(st1);
                    const float4 w2 = win11x4(spt1);
                    const float4 w3 = win11x4(ssq1);
                    const uint2 q0 = pack4h(w0.x, w1.x, w2.x, w3.x);
                    const uint2 q1 = pack4h(w0.y, w1.y, w2.y, w3.y);
                    const uint2 q2 = pack4h(w0.z, w1.z, w2.z, w3.z);
                    const uint2 q3 = pack4h(w0.w, w1.w, w2.w, w3.w);
                    uint4* o4 = reinterpret_cast<uint4*>(outp1);
                    o4[0] = make_uint4(q0.x, q0.y, q1.x, q1.y);
                    o4[1] = make_uint4(q2.x, q2.y, q3.x, q3.y);
                    outp1 += PLANE;
                }
            }
        }
    }

    l1 += __shfl_xor(l1, 32);
    l1 += __shfl_xor(l1, 16);
    l1 += __shfl_xor(l1, 8);
    l1 += __shfl_xor(l1, 4);
    l1 += __shfl_xor(l1, 2);
    l1 += __shfl_xor(l1, 1);
    if (l == 0) slotW[logical * WPB + wid] = (double)l1;
}

// K3: wide-load ringless z-pass (verified R19/R21). ZCH=12 (measured best).
// Block = (b, y-pair, z-chunk), 144 threads.
__global__ void k3_zpass(const uint2* __restrict__ wsh, double* __restrict__ slotS) {
    const int t = threadIdx.x;
    int bid = blockIdx.x;
    const int c = bid % ZCH; bid /= ZCH;
    const int yp = bid % (W / 2); bid /= (W / 2);
    const int b = bid;
    const int y = 2 * yp + (t / 72);
    const int xp = t % 72;
    const int zstart = c * ZCL;

    const uint2* F = wsh + (size_t)b * VOL + (size_t)y * PLANE + 2 * xp;

    float a0 = 0.f, a1 = 0.f, a2 = 0.f, a3 = 0.f;
    float b0 = 0.f, b1 = 0.f, b2 = 0.f, b3 = 0.f;
    const float inv = 1.0f / 1331.0f;
    const float C1 = 0.01f * 0.01f;
    const float C2 = 0.03f * 0.03f;
    float ssim_acc = 0.f;

    const int NZ = ZCL + 2 * PAD;  // 22
#pragma unroll 1
    for (int i = 0; i < NZ; ++i) {
        const int zl = zstart - PAD + i;
        if (zl >= 0 && zl < W) {
            const uint4 uu = *reinterpret_cast<const uint4*>(F + (size_t)zl * W);
            const float4 vA = unpack4h(uu.x, uu.y);
            const float4 vB = unpack4h(uu.z, uu.w);
            a0 += vA.x; a1 += vA.y; a2 += vA.z; a3 += vA.w;
            b0 += vB.x; b1 += vB.y; b2 += vB.z; b3 += vB.w;
        }
        const int zo = zl - WIN;
        if (i >= WIN && zo >= 0) {
            const uint4 uu = *reinterpret_cast<const uint4*>(F + (size_t)zo * W);
            const float4 vA = unpack4h(uu.x, uu.y);
            const float4 vB = unpack4h(uu.z, uu.w);
            a0 -= vA.x; a1 -= vA.y; a2 -= vA.z; a3 -= vA.w;
            b0 -= vB.x; b1 -= vB.y; b2 -= vB.z; b3 -= vB.w;
        }
        if (i >= 2 * PAD) {
            {
                const float mu_p = a0 * inv, mu_t = a1 * inv;
                const float ept = a2 * inv, esq = a3 * inv;
                const float mupt = mu_p * mu_t;
                const float musq = mu_p * mu_p + mu_t * mu_t;
                const float num = (2.f * mupt + C1) * (2.f * (ept - mupt) + C2);
                const float den = (musq + C1) * ((esq - musq) + C2);
                ssim_acc += num / den;
            }
            {
                const float mu_p = b0 * inv, mu_t = b1 * inv;
                const float ept = b2 * inv, esq = b3 * inv;
                const float mupt = mu_p * mu_t;
                const float musq = mu_p * mu_p + mu_t * mu_t;
                const float num = (2.f * mupt + C1) * (2.f * (ept - mupt) + C2);
                const float den = (musq + C1) * ((esq - musq) + C2);
                ssim_acc += num / den;
            }
        }
    }

    __shared__ float red[W];
    red[t] = ssim_acc;
    __syncthreads();
    if (t < 16) {
        float s2r = 0.f;
#pragma unroll
        for (int k = 0; k < 9; ++k) s2r += red[t + 16 * k];
        s2r += __shfl_down(s2r, 8);
        s2r += __shfl_down(s2r, 4);
        s2r += __shfl_down(s2r, 2);
        s2r += __shfl_down(s2r, 1);
        if (t == 0) slotS[blockIdx.x] = (double)s2r;
    }
}

// K4: reduce the 1728 + 1728 slots, write the 3 outputs. Deterministic order.
__global__ void k4_final(const double* __restrict__ slotW,
                         const double* __restrict__ slotS, float* __restrict__ out) {
    const int x = threadIdx.x;
    double a = 0.0, s = 0.0;
    for (int i = x; i < NWAVES; i += 256) a += slotW[i];
    for (int i = x; i < NZB; i += 256) s += slotS[i];
    __shared__ double d1[256];
    __shared__ double d2[256];
    d1[x] = a; d2[x] = s;
    __syncthreads();
    for (int st = 128; st > 0; st >>= 1) {
        if (x < st) { d1[x] += d1[x + st]; d2[x] += d2[x + st]; }
        __syncthreads();
    }
    if (x == 0) {
        const double n = (double)NB * (double)VOL;
        const double l1 = d1[0] / n;
        const double ssim_loss = 1.0 - d2[0] / n;
        out[0] = (float)(l1 + 0.5 * ssim_loss);
        out[1] = (float)l1;
        out[2] = (float)ssim_loss;
    }
}

extern "C" void kernel_launch(void* const* d_in, const int* in_sizes, int n_in,
                              void* d_out, int out_size, void* d_ws, size_t ws_size,
                              hipStream_t stream) {
    const float* pred = (const float*)d_in[0];
    const float* targ = (const float*)d_in[1];
    float* out = (float*)d_out;
    uint2* wsh = (uint2*)d_ws;                                  // half4 per voxel, 47.8 MB
    double* slotW = (double*)((char*)d_ws + (size_t)NB * VOL * sizeof(uint2));
    double* slotS = slotW + NWAVES;

    const int nwg = NWAVES / WPB;  // 432 blocks
    kG_xypass<<<nwg, WPB * 64, 0, stream>>>(pred, targ, wsh, slotW);
    k3_zpass<<<NZB, W, 0, stream>>>(wsh, slotS);
    k4_final<<<1, 256, 0, stream>>>(slotW, slotS, out);
}

// Round 25
// 61.715 us; speedup vs baseline: 1.0547x; 1.0183x over previous
//
#include <hip/hip_runtime.h>
#include <hip/hip_fp16.h>

#define W 144
#define PLANE (W * W)
#define VOL (W * W * W)
#define NB 2
#define WIN 11
#define PAD 5
#define YCH 9
#define YC (W / YCH)           // 16
#define NSTEPS (YC + 2 * PAD)  // 26
#define ZCH 12
#define ZCL (W / ZCH)          // 12
#define WPB 4
#define NXCD 8
#define NWAVES (NB * W * YCH)        // 2592
#define NZB (NB * (W / 2) * ZCH)     // 1728

// DPP lane shift with old=0 (edge/exec-off lanes read 0).
template <int CTRL>
__device__ __forceinline__ float dpp0(float x) {
    return __int_as_float(
        __builtin_amdgcn_update_dpp(0, __float_as_int(x), CTRL, 0xf, 0xf, false));
}
#define SHR1(v) dpp0<0x138>(v)
#define SHL1(v) dpp0<0x130>(v)

// Lane l holds v at x = 4l-8 .. 4l-5. 11-tap x-window sums for its 4 positions
// using only wave shifts (verified on-chip R8/R12/R13/R14, absmax 0).
__device__ __forceinline__ float4 win11x4(const float4 v) {
    const float pre2 = v.x + v.y;
    const float pre3 = pre2 + v.z;
    const float q = pre3 + v.w;
    const float suf2 = v.z + v.w;
    const float suf3 = suf2 + v.y;
    const float qm1 = SHR1(q);
    const float sfx2m1 = SHR1(suf2);
    const float sfx3m1 = SHR1(suf3);
    const float sfx1m2 = SHR1(SHR1(v.w));
    const float qp1 = SHL1(q);
    const float pfx2p1 = SHL1(pre2);
    const float pfx3p1 = SHL1(pre3);
    const float pfx1p2 = SHL1(SHL1(v.x));
    float4 w;
    w.x = (sfx1m2 + qm1) + (q + pfx2p1);
    w.y = qm1 + (q + pfx3p1);
    w.z = sfx3m1 + (q + qp1);
    w.w = (sfx2m1 + q) + (qp1 + pfx1p2);
    return w;
}

__device__ __forceinline__ uint2 pack4h(float a, float b, float c, float d) {
    const __half2 lo = __floats2half2_rn(a, b);
    const __half2 hi = __floats2half2_rn(c, d);
    uint2 r;
    r.x = __builtin_bit_cast(unsigned int, lo);
    r.y = __builtin_bit_cast(unsigned int, hi);
    return r;
}

__device__ __forceinline__ float4 unpack4h(unsigned int lo, unsigned int hi) {
    const float2 flo = __half22float2(__builtin_bit_cast(__half2, lo));
    const float2 fhi = __half22float2(__builtin_bit_cast(__half2, hi));
    return make_float4(flo.x, flo.y, fhi.x, fhi.y);
}

// kF: ringless fat-4 x+y pass, ROLLED 26-step loop, fp16 ws in [b][y][z][x]
// layout. Best end-to-end measured config (R21: 61.8 us total).
__global__ __launch_bounds__(WPB * 64) void
kF_xypass(const float* __restrict__ pred, const float* __restrict__ targ,
          uint2* __restrict__ wsh, double* __restrict__ slotW) {
    const int tid = threadIdx.x;
    const int l = tid & 63;
    const int wid = tid >> 6;

    // bijective XCD swizzle (nwg % 8 == 0)
    const int nwg = NWAVES / WPB;         // 648
    const int q = nwg / NXCD;             // 81
    const int hw = (int)blockIdx.x;
    const int logical = (hw % NXCD) * q + hw / NXCD;

    int wg = logical * WPB + wid;
    const int yc = wg % YCH; wg /= YCH;
    const int z = wg % W; wg /= W;
    const int b = wg;
    const int y0 = yc * YC;

    const int xbase = 4 * l - 8;                 // lanes 2..37 own x 0..143
    const bool vx = (xbase >= 0) && (xbase < W);
    const float* __restrict__ gp = pred + (size_t)b * VOL + (size_t)z * PLANE + xbase;
    const float* __restrict__ gt = targ + (size_t)b * VOL + (size_t)z * PLANE + xbase;

    const float4 z4 = make_float4(0.f, 0.f, 0.f, 0.f);
    float l1 = 0.f;

    if (vx) {
        float4 s_p = z4, s_t = z4, s_pt = z4, s_sq = z4;
        float4 pa = z4, ta = z4, pn = z4, tn = z4, po = z4, to = z4;

        {
            const int g0 = y0 - PAD;
            if (g0 >= 0) {
                pa = *reinterpret_cast<const float4*>(gp + (size_t)g0 * W);
                ta = *reinterpret_cast<const float4*>(gt + (size_t)g0 * W);
            }
            const int g1 = y0 - PAD + 1;
            if (g1 >= 0) {
                pn = *reinterpret_cast<const float4*>(gp + (size_t)g1 * W);
                tn = *reinterpret_cast<const float4*>(gt + (size_t)g1 * W);
            }
        }

        uint2* outp = wsh + (size_t)b * VOL + (size_t)y0 * PLANE + (size_t)z * W + xbase;

#pragma unroll 1
        for (int i = 0; i < NSTEPS; ++i) {
            const float4 p4 = pa, t4 = ta;
            pa = pn; ta = tn;
            {
                const int g = y0 - PAD + i + 2;
                if (i < NSTEPS - 2 && g >= 0 && g < W) {
                    pn = *reinterpret_cast<const float4*>(gp + (size_t)g * W);
                    tn = *reinterpret_cast<const float4*>(gt + (size_t)g * W);
                } else {
                    pn = z4; tn = z4;
                }
            }

            if (i >= PAD && i < PAD + YC) {
                l1 += (fabsf(p4.x - t4.x) + fabsf(p4.y - t4.y)) +
                      (fabsf(p4.z - t4.z) + fabsf(p4.w - t4.w));
            }

            s_p.x += p4.x; s_p.y += p4.y; s_p.z += p4.z; s_p.w += p4.w;
            s_t.x += t4.x; s_t.y += t4.y; s_t.z += t4.z; s_t.w += t4.w;
            s_pt.x += p4.x * t4.x; s_pt.y += p4.y * t4.y;
            s_pt.z += p4.z * t4.z; s_pt.w += p4.w * t4.w;
            s_sq.x += fmaf(p4.x, p4.x, t4.x * t4.x);
            s_sq.y += fmaf(p4.y, p4.y, t4.y * t4.y);
            s_sq.z += fmaf(p4.z, p4.z, t4.z * t4.z);
            s_sq.w += fmaf(p4.w, p4.w, t4.w * t4.w);

            if (i >= WIN) {
                s_p.x -= po.x; s_p.y -= po.y; s_p.z -= po.z; s_p.w -= po.w;
                s_t.x -= to.x; s_t.y -= to.y; s_t.z -= to.z; s_t.w -= to.w;
                s_pt.x -= po.x * to.x; s_pt.y -= po.y * to.y;
                s_pt.z -= po.z * to.z; s_pt.w -= po.w * to.w;
                s_sq.x -= fmaf(po.x, po.x, to.x * to.x);
                s_sq.y -= fmaf(po.y, po.y, to.y * to.y);
                s_sq.z -= fmaf(po.z, po.z, to.z * to.z);
                s_sq.w -= fmaf(po.w, po.w, to.w * to.w);
            }

            if (i >= 2 * PAD) {
                if (i < NSTEPS - 1) {  // prefetch old row for step i+1's subtract
                    const int g = y0 + i - 15;  // (i+1) - 11 - PAD + y0
                    if (g >= 0) {
                        po = *reinterpret_cast<const float4*>(gp + (size_t)g * W);
                        to = *reinterpret_cast<const float4*>(gt + (size_t)g * W);
                    } else {
                        po = z4; to = z4;
                    }
                }
                const float4 w0 = win11x4(s_p);
                const float4 w1 = win11x4(s_t);
                const float4 w2 = win11x4(s_pt);
                const float4 w3 = win11x4(s_sq);
                const uint2 q0 = pack4h(w0.x, w1.x, w2.x, w3.x);
                const uint2 q1 = pack4h(w0.y, w1.y, w2.y, w3.y);
                const uint2 q2 = pack4h(w0.z, w1.z, w2.z, w3.z);
                const uint2 q3 = pack4h(w0.w, w1.w, w2.w, w3.w);
                uint4* o4 = reinterpret_cast<uint4*>(outp);
                o4[0] = make_uint4(q0.x, q0.y, q1.x, q1.y);
                o4[1] = make_uint4(q2.x, q2.y, q3.x, q3.y);
                outp += PLANE;
            }
        }
    }

    l1 += __shfl_xor(l1, 32);
    l1 += __shfl_xor(l1, 16);
    l1 += __shfl_xor(l1, 8);
    l1 += __shfl_xor(l1, 4);
    l1 += __shfl_xor(l1, 2);
    l1 += __shfl_xor(l1, 1);
    if (l == 0) slotW[logical * WPB + wid] = (double)l1;
}

// K3: wide-load ringless z-pass (verified R19/R21). ZCH=12 (measured best).
// Block = (b, y-pair, z-chunk), 144 threads.
__global__ void k3_zpass(const uint2* __restrict__ wsh, double* __restrict__ slotS) {
    const int t = threadIdx.x;
    int bid = blockIdx.x;
    const int c = bid % ZCH; bid /= ZCH;
    const int yp = bid % (W / 2); bid /= (W / 2);
    const int b = bid;
    const int y = 2 * yp + (t / 72);
    const int xp = t % 72;
    const int zstart = c * ZCL;

    const uint2* F = wsh + (size_t)b * VOL + (size_t)y * PLANE + 2 * xp;

    float a0 = 0.f, a1 = 0.f, a2 = 0.f, a3 = 0.f;
    float b0 = 0.f, b1 = 0.f, b2 = 0.f, b3 = 0.f;
    const float inv = 1.0f / 1331.0f;
    const float C1 = 0.01f * 0.01f;
    const float C2 = 0.03f * 0.03f;
    float ssim_acc = 0.f;

    const int NZ = ZCL + 2 * PAD;  // 22
#pragma unroll 1
    for (int i = 0; i < NZ; ++i) {
        const int zl = zstart - PAD + i;
        if (zl >= 0 && zl < W) {
            const uint4 uu = *reinterpret_cast<const uint4*>(F + (size_t)zl * W);
            const float4 vA = unpack4h(uu.x, uu.y);
            const float4 vB = unpack4h(uu.z, uu.w);
            a0 += vA.x; a1 += vA.y; a2 += vA.z; a3 += vA.w;
            b0 += vB.x; b1 += vB.y; b2 += vB.z; b3 += vB.w;
        }
        const int zo = zl - WIN;
        if (i >= WIN && zo >= 0) {
            const uint4 uu = *reinterpret_cast<const uint4*>(F + (size_t)zo * W);
            const float4 vA = unpack4h(uu.x, uu.y);
            const float4 vB = unpack4h(uu.z, uu.w);
            a0 -= vA.x; a1 -= vA.y; a2 -= vA.z; a3 -= vA.w;
            b0 -= vB.x; b1 -= vB.y; b2 -= vB.z; b3 -= vB.w;
        }
        if (i >= 2 * PAD) {
            {
                const float mu_p = a0 * inv, mu_t = a1 * inv;
                const float ept = a2 * inv, esq = a3 * inv;
                const float mupt = mu_p * mu_t;
                const float musq = mu_p * mu_p + mu_t * mu_t;
                const float num = (2.f * mupt + C1) * (2.f * (ept - mupt) + C2);
                const float den = (musq + C1) * ((esq - musq) + C2);
                ssim_acc += num / den;
            }
            {
                const float mu_p = b0 * inv, mu_t = b1 * inv;
                const float ept = b2 * inv, esq = b3 * inv;
                const float mupt = mu_p * mu_t;
                const float musq = mu_p * mu_p + mu_t * mu_t;
                const float num = (2.f * mupt + C1) * (2.f * (ept - mupt) + C2);
                const float den = (musq + C1) * ((esq - musq) + C2);
                ssim_acc += num / den;
            }
        }
    }

    __shared__ float red[W];
    red[t] = ssim_acc;
    __syncthreads();
    if (t < 16) {
        float s2r = 0.f;
#pragma unroll
        for (int k = 0; k < 9; ++k) s2r += red[t + 16 * k];
        s2r += __shfl_down(s2r, 8);
        s2r += __shfl_down(s2r, 4);
        s2r += __shfl_down(s2r, 2);
        s2r += __shfl_down(s2r, 1);
        if (t == 0) slotS[blockIdx.x] = (double)s2r;
    }
}

// K4: reduce the 2592 + 1728 slots, write the 3 outputs. Deterministic order.
__global__ void k4_final(const double* __restrict__ slotW,
                         const double* __restrict__ slotS, float* __restrict__ out) {
    const int x = threadIdx.x;
    double a = 0.0, s = 0.0;
    for (int i = x; i < NWAVES; i += 256) a += slotW[i];
    for (int i = x; i < NZB; i += 256) s += slotS[i];
    __shared__ double d1[256];
    __shared__ double d2[256];
    d1[x] = a; d2[x] = s;
    __syncthreads();
    for (int st = 128; st > 0; st >>= 1) {
        if (x < st) { d1[x] += d1[x + st]; d2[x] += d2[x + st]; }
        __syncthreads();
    }
    if (x == 0) {
        const double n = (double)NB * (double)VOL;
        const double l1 = d1[0] / n;
        const double ssim_loss = 1.0 - d2[0] / n;
        out[0] = (float)(l1 + 0.5 * ssim_loss);
        out[1] = (float)l1;
        out[2] = (float)ssim_loss;
    }
}

extern "C" void kernel_launch(void* const* d_in, const int* in_sizes, int n_in,
                              void* d_out, int out_size, void* d_ws, size_t ws_size,
                              hipStream_t stream) {
    const float* pred = (const float*)d_in[0];
    const float* targ = (const float*)d_in[1];
    float* out = (float*)d_out;
    uint2* wsh = (uint2*)d_ws;                                  // half4 per voxel, 47.8 MB
    double* slotW = (double*)((char*)d_ws + (size_t)NB * VOL * sizeof(uint2));
    double* slotS = slotW + NWAVES;

    const int nwg = NWAVES / WPB;  // 648 blocks
    kF_xypass<<<nwg, WPB * 64, 0, stream>>>(pred, targ, wsh, slotW);
    k3_zpass<<<NZB, W, 0, stream>>>(wsh, slotS);
    k4_final<<<1, 256, 0, stream>>>(slotW, slotS, out);
}